// Round 1
// baseline (25.519 us; speedup 1.0000x reference)
//
#include <hip/hip_runtime.h>

namespace {
constexpr int kB   = 2;
constexpr int kC   = 64;
constexpr int kH   = 128;
constexpr int kW   = 240;
constexpr int kD0  = 16;          // disps 0,3,...,45
constexpr int kD1  = 5;           // disps -2,-1,0,1,2
constexpr int kWc1 = kW + 45;     // 285
constexpr int kWc2 = kW + 2;      // 242
constexpr int kPad = 48;          // >= max disp 45, 16B-aligned float offset
constexpr int kRow = 336;         // >= kPad + kWc1 (333), 16B-aligned stride
constexpr int kThreads = 320;     // 5 waves; >= kWc1
constexpr int kOut1 = kB * kD0 * kH * kWc1;  // 1,167,360 floats
}

__global__ __launch_bounds__(kThreads)
void anynet_disp_kernel(const float* __restrict__ fr, float* __restrict__ out) {
  __shared__ float P[kC * kRow];  // 86,016 B: exp(feat_r) padded with ones
  const int bh = blockIdx.x;      // 0..255
  const int b  = bh >> 7;
  const int h  = bh & 127;
  const int t  = threadIdx.x;

  // ---- fill pad regions with 1.0 (= exp(0), the "invalid disparity" value)
  // per row: j in [0,48) and [288,336)  -> 96 floats/row
  for (int i = t; i < kC * 96; i += kThreads) {
    const int row = i / 96;
    const int off = i % 96;
    const int j   = (off < kPad) ? off : off + kW;  // off+240 -> [288,336)
    P[row * kRow + j] = 1.0f;
  }

  // ---- stage exp(feat_r[b, :, h, :]) as float4 (64 rows x 60 float4 = 3840;
  //      3840/320 = 12 iters/thread, fully coalesced)
  for (int i = t; i < kC * (kW / 4); i += kThreads) {
    const int row = i / 60;
    const int xq  = i % 60;
    const float4 v =
        reinterpret_cast<const float4*>(fr)[(((b * kC + row) * kH + h) * kW) / 4 + xq];
    float4 e;
    e.x = __expf(v.x); e.y = __expf(v.y); e.z = __expf(v.z); e.w = __expf(v.w);
    reinterpret_cast<float4*>(&P[row * kRow + kPad])[xq] = e;
  }
  __syncthreads();

  if (t >= kWc1) return;

  float acc1[kD0] = {};
  float acc2[kD1] = {};
  const int tb = kPad + t;

  #pragma unroll 2
  for (int c = 0; c < kC; ++c) {
    const float* __restrict__ row = &P[c * kRow];

    // out1: disparities 3k, k=0..15
    float v[kD0];
    float s = 0.0f;
    #pragma unroll
    for (int k = 0; k < kD0; ++k) { v[k] = row[tb - 3 * k]; s += v[k]; }
    const float r = __builtin_amdgcn_rcpf(s);
    #pragma unroll
    for (int k = 0; k < kD0; ++k) acc1[k] = fmaf(v[k], r, acc1[k]);

    // out2: disparities -2..2 (offsets +2..-2); computed for all t<285,
    // stores guarded below (pad reads stay in-range: tb+2 <= 334 < 336)
    float u[kD1];
    float s2 = 0.0f;
    #pragma unroll
    for (int j = 0; j < kD1; ++j) { u[j] = row[tb + 2 - j]; s2 += u[j]; }
    const float r2 = __builtin_amdgcn_rcpf(s2);
    #pragma unroll
    for (int j = 0; j < kD1; ++j) acc2[j] = fmaf(u[j], r2, acc2[j]);
  }

  // ---- epilogue: out[b,d,0,h,w] = disp[d] * (C/D + acc[d])
  #pragma unroll
  for (int d = 0; d < kD0; ++d) {
    out[((b * kD0 + d) * kH + h) * kWc1 + t] =
        (3.0f * (float)d) * (4.0f + acc1[d]);       // C/D0 = 64/16 = 4
  }
  if (t < kWc2) {
    float* __restrict__ o2 = out + kOut1;
    #pragma unroll
    for (int j = 0; j < kD1; ++j) {
      o2[((b * kD1 + j) * kH + h) * kWc2 + t] =
          (float)(j - 2) * (64.0f / 5.0f + acc2[j]); // C/D1 = 12.8
    }
  }
}

extern "C" void kernel_launch(void* const* d_in, const int* in_sizes, int n_in,
                              void* d_out, int out_size, void* d_ws, size_t ws_size,
                              hipStream_t stream) {
  const float* feat_r = (const float*)d_in[1];  // feats_l (d_in[0]) is unused:
                                                // left channels contribute exactly C/D
  float* out = (float*)d_out;
  anynet_disp_kernel<<<dim3(kB * kH), dim3(kThreads), 0, stream>>>(feat_r, out);
}

// Round 2
// 19.642 us; speedup vs baseline: 1.2992x; 1.2992x over previous
//
#include <hip/hip_runtime.h>

namespace {
constexpr int kB   = 2;
constexpr int kC   = 64;
constexpr int kH   = 128;
constexpr int kW   = 240;
constexpr int kD0  = 16;          // disps 0,3,...,45
constexpr int kD1  = 5;           // disps -2,-1,0,1,2
constexpr int kWc1 = kW + 45;     // 285
constexpr int kWc2 = kW + 2;      // 242
constexpr int kPad = 48;          // >= max disp 45, 16B-aligned float offset
constexpr int kRow = 336;         // >= kPad + kWc1 (333), 16B-aligned stride
constexpr int kGroups   = 3;      // channel-parallel groups within a block
constexpr int kGThreads = 320;    // threads per group (>= kWc1)
constexpr int kThreads  = kGroups * kGThreads;  // 960 = 15 waves
constexpr int kAcc  = kD0 + kD1;  // 21 accumulators per column
constexpr int kRStr = kWc1 * kAcc;            // 5985 floats per group partial
constexpr int kSFl  = kC * kRow;              // 21504 floats = 86016 B (>= 3*kRStr)
constexpr int kOut1 = kB * kD0 * kH * kWc1;   // 1,167,360 floats
constexpr int kN1   = kD0 * kWc1;             // 4560 out1 items per (b,h)
constexpr int kN2   = kD1 * kWc2;             // 1210 out2 items per (b,h)
}

__global__ __launch_bounds__(kThreads)
void anynet_disp_kernel(const float* __restrict__ fr, float* __restrict__ out) {
  __shared__ float S[kSFl];       // phase A: exp(feat_r) padded; phase B: partials
  const int bh  = blockIdx.x;     // 0..255
  const int b   = bh >> 7;
  const int h   = bh & 127;
  const int tid = threadIdx.x;

  // ---- phase A0: pad regions = 1.0 (= exp(0), the "invalid" cost value)
  for (int i = tid; i < kC * 96; i += kThreads) {
    const int row = i / 96;
    const int off = i % 96;
    const int j   = (off < kPad) ? off : off + kW;  // [0,48) and [288,336)
    S[row * kRow + j] = 1.0f;
  }
  // ---- phase A1: stage exp(feat_r[b,:,h,:]) as float4 (3840 items / 960 thr)
  for (int i = tid; i < kC * (kW / 4); i += kThreads) {
    const int row = i / 60;
    const int xq  = i % 60;
    const float4 v =
        reinterpret_cast<const float4*>(fr)[(((b * kC + row) * kH + h) * kW) / 4 + xq];
    float4 e;
    e.x = __expf(v.x); e.y = __expf(v.y); e.z = __expf(v.z); e.w = __expf(v.w);
    reinterpret_cast<float4*>(&S[row * kRow + kPad])[xq] = e;
  }
  __syncthreads();

  // ---- phase B: each group handles a channel slice, accumulating in regs
  const int g = tid / kGThreads;        // 0..2
  const int t = tid % kGThreads;        // column
  float acc1[kD0] = {};
  float acc2[kD1] = {};
  if (t < kWc1) {
    const int cbeg = (g == 0) ? 0 : 22 + (g - 1) * 21;
    const int cend = (g == 0) ? 22 : cbeg + 21;
    const int tb = kPad + t;
    for (int c = cbeg; c < cend; ++c) {
      const float* __restrict__ row = &S[c * kRow];
      float v[kD0];
      float s = 0.0f;
      #pragma unroll
      for (int k = 0; k < kD0; ++k) { v[k] = row[tb - 3 * k]; s += v[k]; }
      const float r = __builtin_amdgcn_rcpf(s);
      #pragma unroll
      for (int k = 0; k < kD0; ++k) acc1[k] = fmaf(v[k], r, acc1[k]);

      float u[kD1];
      float s2 = 0.0f;
      #pragma unroll
      for (int j = 0; j < kD1; ++j) { u[j] = row[tb + 2 - j]; s2 += u[j]; }
      const float r2 = __builtin_amdgcn_rcpf(s2);
      #pragma unroll
      for (int j = 0; j < kD1; ++j) acc2[j] = fmaf(u[j], r2, acc2[j]);
    }
  }
  __syncthreads();   // all reads of staged E complete; S reusable

  // ---- phase C: dump per-group partials (stride 21 -> conflict-free)
  if (t < kWc1) {
    float* __restrict__ R = &S[g * kRStr + t * kAcc];
    #pragma unroll
    for (int k = 0; k < kD0; ++k) R[k] = acc1[k];
    #pragma unroll
    for (int j = 0; j < kD1; ++j) R[kD0 + j] = acc2[j];
  }
  __syncthreads();

  // ---- phase D: combine 3 partials, write coalesced (col fastest)
  for (int i = tid; i < kN1 + kN2; i += kThreads) {
    if (i < kN1) {
      const int d   = i / kWc1;
      const int col = i % kWc1;
      const int o   = col * kAcc + d;
      const float v = S[o] + S[kRStr + o] + S[2 * kRStr + o];
      out[((b * kD0 + d) * kH + h) * kWc1 + col] =
          (3.0f * (float)d) * (4.0f + v);            // C/D0 = 4
    } else {
      const int i2  = i - kN1;
      const int j   = i2 / kWc2;
      const int col = i2 % kWc2;
      const int o   = col * kAcc + kD0 + j;
      const float v = S[o] + S[kRStr + o] + S[2 * kRStr + o];
      out[kOut1 + ((b * kD1 + j) * kH + h) * kWc2 + col] =
          (float)(j - 2) * (64.0f / 5.0f + v);       // C/D1 = 12.8
    }
  }
}

extern "C" void kernel_launch(void* const* d_in, const int* in_sizes, int n_in,
                              void* d_out, int out_size, void* d_ws, size_t ws_size,
                              hipStream_t stream) {
  const float* feat_r = (const float*)d_in[1];  // feats_l contributes exactly C/D
  float* out = (float*)d_out;
  anynet_disp_kernel<<<dim3(kB * kH), dim3(kThreads), 0, stream>>>(feat_r, out);
}